// Round 10
// baseline (237.023 us; speedup 1.0000x reference)
//
#include <hip/hip_runtime.h>
#include <hip/hip_bf16.h>

#define DF   128      // feature dim
#define DPC  16       // dims per capsule (8 caps)
#define WPB  4        // waves per 256-thread block
#define EPT  4        // edges per thread in k_bucket

// ---------- helpers ----------
__device__ __forceinline__ float cap_sum(float v) {   // sum over lanes l..l|7
    v += __shfl_xor(v, 1);
    v += __shfl_xor(v, 2);
    v += __shfl_xor(v, 4);
    return v;
}
__device__ __forceinline__ float bits_lo(unsigned int w) {
    union { unsigned int u; float f; } c; c.u = w << 16; return c.f;
}
__device__ __forceinline__ float bits_hi(unsigned int w) {
    union { unsigned int u; float f; } c; c.u = w & 0xFFFF0000u; return c.f;
}
__device__ __forceinline__ unsigned int f2b_pack(float lo, float hi) {
    __hip_bfloat16 a = __float2bfloat16(lo), b = __float2bfloat16(hi);
    unsigned short ua = *reinterpret_cast<unsigned short*>(&a);
    unsigned short ub = *reinterpret_cast<unsigned short*>(&b);
    return ((unsigned int)ub << 16) | ua;
}
__device__ __forceinline__ float2 load_x2(const void* __restrict__ xraw, int fp32,
                                          int node, int lane) {
    size_t off = (size_t)node * DF + (size_t)lane * 2;
    if (fp32) {
        return *reinterpret_cast<const float2*>((const float*)xraw + off);
    } else {
        unsigned int w = ((const unsigned int*)xraw)[(size_t)node * 64 + lane];
        return make_float2(bits_lo(w), bits_hi(w));
    }
}
__device__ __forceinline__ int2 edge_st(const int* __restrict__ ei, int i64,
                                        int e, int n_edges) {
    size_t si = i64 ? (size_t)2 * e             : (size_t)e;
    size_t ti = i64 ? (size_t)2 * (n_edges + e) : (size_t)(n_edges + e);
    return make_int2(ei[si], ei[ti]);
}

// ---------- 1: detect dtypes (block 0) + zero cnt (blocks 1..) ----------
__global__ void k_detect_zero(const unsigned int* __restrict__ xw,
                              const unsigned int* __restrict__ ew,
                              int* __restrict__ flags, int* __restrict__ cnt,
                              int n_nodes) {
    if (blockIdx.x == 0) {
        __shared__ int s_nan, s_zero;
        int tid = threadIdx.x;
        if (tid == 0) { s_nan = 0; s_zero = 0; }
        __syncthreads();
        int cnt_nan = 0;
        for (int i = tid; i < 4096; i += 256) {       // P(fp32 miss) ~ e^-16
            unsigned int lo = xw[i] & 0xFFFFu;
            if ((lo & 0x7F80u) == 0x7F80u) cnt_nan++; // impossible in bf16 data
        }
        int cnt_zero = 0;
        for (int i = tid; i < 1024; i += 256) {
            if (ew[2 * i + 1] == 0u) cnt_zero++;      // int64 high words zero
        }
        atomicAdd(&s_nan, cnt_nan);
        atomicAdd(&s_zero, cnt_zero);
        __syncthreads();
        if (tid == 0) {
            flags[0] = (s_nan > 0) ? 1 : 0;   // x is fp32
            flags[1] = (s_zero > 512) ? 1 : 0; // edge_index is int64
        }
    } else {
        int i = (blockIdx.x - 1) * 256 + threadIdx.x;
        if (i < n_nodes) cnt[i] = 0;
    }
}

// ---------- 2: xc = bf16(per-capsule l2norm(x)), swizzled row layout --------
// Row (256 B): words [0,32) = caps' dims 0..7 (cap-major, 4 words each),
//              words [32,64) = caps' dims 8..15. So in k_route, lane (slot,c)
// load1 hits a contiguous 128 B block across the 8 caps, load2 the other.
__global__ void k_xc(const void* __restrict__ xraw, unsigned int* __restrict__ xcb,
                     const int* __restrict__ flags, int n_nodes) {
    int wid  = (blockIdx.x * blockDim.x + threadIdx.x) >> 6;
    int lane = threadIdx.x & 63;
    if (wid >= n_nodes) return;
    float2 v = load_x2(xraw, flags[0], wid, lane);
    float ss = cap_sum(v.x * v.x + v.y * v.y);
    float scale = 1.0f / fmaxf(sqrtf(ss), 1e-12f);
    int c = lane >> 3, jp = lane & 7;        // capsule, dim-pair within capsule
    int w = (jp < 4) ? (c * 4 + jp) : (32 + c * 4 + (jp - 4));
    xcb[(size_t)wid * 64 + w] = f2b_pack(v.x * scale, v.y * scale);
}

// ---------- 3: single-pass edge bucketing, 4 edges/thread ILP ----------
// Phase A: load 4 (s,t) pairs. Phase B: 4 independent atomics (all in flight).
// Phase C: 4 dependent scatter writes.
__global__ void k_bucket(const int* __restrict__ ei, int* __restrict__ cnt,
                         int* __restrict__ elist, const int* __restrict__ flags,
                         int n_edges, int n_nodes, int K) {
    const int i64 = flags[1];
    int base = blockIdx.x * (256 * EPT) + threadIdx.x;
    int s[EPT], t[EPT], slot[EPT];
    bool ok[EPT];
    #pragma unroll
    for (int k = 0; k < EPT; ++k) {
        int e = base + k * 256;
        if (e < n_edges) {
            int2 st = edge_st(ei, i64, e, n_edges);
            s[k] = st.x; t[k] = st.y;
            ok[k] = (unsigned)st.x < (unsigned)n_nodes &&
                    (unsigned)st.y < (unsigned)n_nodes;
        } else ok[k] = false;
    }
    #pragma unroll
    for (int k = 0; k < EPT; ++k)
        if (ok[k]) slot[k] = atomicAdd(&cnt[t[k]], 1);
    #pragma unroll
    for (int k = 0; k < EPT; ++k)
        if (ok[k] && slot[k] < K)
            elist[t[k] * K + slot[k]] = s[k] << 8;   // byte offset of 256B row
}

// ---------- 4: fused 3-iteration routing ----------
// One wave per target. Lane = e8*8 + c: 8 edge slots x 8 capsules.
// Neighbor rows bf16 swizzled (load1 -> first 128B half, load2 -> second).
__global__ void k_route(const int* __restrict__ cnt, const int* __restrict__ elist,
                        const unsigned int* __restrict__ xcb,
                        const void* __restrict__ xraw, const int* __restrict__ flags,
                        float* __restrict__ u_out, int n_nodes, int K) {
    int t    = (blockIdx.x * blockDim.x + threadIdx.x) >> 6;
    int lane = threadIdx.x & 63;
    if (t >= n_nodes) return;
    const int e8 = lane >> 3;    // edge slot
    const int c  = lane & 7;     // capsule
    const int fp32 = flags[0];

    // target capsule c: 16 dims fp32-exact (natural layout from pristine x)
    float xt[DPC];
    if (fp32) {
        const float* xp = (const float*)xraw + (size_t)t * DF + c * DPC;
        #pragma unroll
        for (int j = 0; j < DPC; j += 4) {
            float4 v = *reinterpret_cast<const float4*>(xp + j);
            xt[j] = v.x; xt[j+1] = v.y; xt[j+2] = v.z; xt[j+3] = v.w;
        }
    } else {
        const unsigned int* xp = (const unsigned int*)xraw + (size_t)t * 64 + c * 8;
        #pragma unroll
        for (int j = 0; j < DPC; j += 8) {
            uint4 w = *reinterpret_cast<const uint4*>(xp + j / 2);
            xt[j]   = bits_lo(w.x); xt[j+1] = bits_hi(w.x);
            xt[j+2] = bits_lo(w.y); xt[j+3] = bits_hi(w.y);
            xt[j+4] = bits_lo(w.z); xt[j+5] = bits_hi(w.z);
            xt[j+6] = bits_lo(w.w); xt[j+7] = bits_hi(w.w);
        }
    }
    float ss = 0.0f;
    #pragma unroll
    for (int j = 0; j < DPC; ++j) ss = fmaf(xt[j], xt[j], ss);
    float sc = 1.0f / fmaxf(sqrtf(ss), 1e-12f);
    float u[DPC];
    #pragma unroll
    for (int j = 0; j < DPC; ++j) { xt[j] *= sc; u[j] = xt[j]; }

    int deg = __builtin_amdgcn_readfirstlane(cnt[t]);
    deg = min(deg, K);
    const int* __restrict__ erow = elist + (size_t)t * K;
    const char* __restrict__ xb  = (const char*)xcb;
    const int coff = c * 16;     // byte offset within each 128 B half

    uint4 cw0, cw1;   // this lane's 2x16 B (dims 0..7 | dims 8..15 of cap c)
    if (deg > 0) {
        int off0 = erow[e8 < deg ? e8 : 0];
        cw0 = *reinterpret_cast<const uint4*>(xb + off0 + coff);
        cw1 = *reinterpret_cast<const uint4*>(xb + off0 + 128 + coff);
    }

    for (int it = 0; it < 3; ++it) {
        float acc[DPC];
        #pragma unroll
        for (int j = 0; j < DPC; ++j) acc[j] = 0.0f;

        for (int base = 0; base < deg; base += 8) {
            uint4 nw0, nw1;
            bool havenext = (base + 8 < deg);
            bool pf = havenext || (it < 2);
            if (pf) {
                int ni = (havenext ? base + 8 : 0) + e8;
                int offn = erow[ni < deg ? ni : 0];
                nw0 = *reinterpret_cast<const uint4*>(xb + offn + coff);
                nw1 = *reinterpret_cast<const uint4*>(xb + offn + 128 + coff);
            }
            float z[DPC];
            z[0]  = bits_lo(cw0.x); z[1]  = bits_hi(cw0.x);
            z[2]  = bits_lo(cw0.y); z[3]  = bits_hi(cw0.y);
            z[4]  = bits_lo(cw0.z); z[5]  = bits_hi(cw0.z);
            z[6]  = bits_lo(cw0.w); z[7]  = bits_hi(cw0.w);
            z[8]  = bits_lo(cw1.x); z[9]  = bits_hi(cw1.x);
            z[10] = bits_lo(cw1.y); z[11] = bits_hi(cw1.y);
            z[12] = bits_lo(cw1.z); z[13] = bits_hi(cw1.z);
            z[14] = bits_lo(cw1.w); z[15] = bits_hi(cw1.w);
            bool valid = (base + e8) < deg;
            float p = 0.0f;
            #pragma unroll
            for (int j = 0; j < DPC; ++j) p = fmaf(z[j], u[j], p);
            // softmax over 8 caps, no max-subtraction: |p|<=~1, exp in [.36,2.8]
            float ex = __expf(p);
            float sd = ex;
            sd += __shfl_xor(sd, 1);
            sd += __shfl_xor(sd, 2);
            sd += __shfl_xor(sd, 4);
            float w = valid ? ex * __builtin_amdgcn_rcpf(sd) : 0.0f;
            #pragma unroll
            for (int j = 0; j < DPC; ++j) acc[j] = fmaf(w, z[j], acc[j]);
            if (pf) { cw0 = nw0; cw1 = nw1; }
        }
        // reduce across the 8 edge slots (lane bits 3..5)
        #pragma unroll
        for (int j = 0; j < DPC; ++j) {
            acc[j] += __shfl_xor(acc[j], 8);
            acc[j] += __shfl_xor(acc[j], 16);
            acc[j] += __shfl_xor(acc[j], 32);
        }
        // residual + per-capsule l2norm, in-lane
        float s2 = 0.0f;
        #pragma unroll
        for (int j = 0; j < DPC; ++j) {
            u[j] = acc[j] + xt[j];
            s2 = fmaf(u[j], u[j], s2);
        }
        float sc2 = 1.0f / fmaxf(sqrtf(s2), 1e-12f);
        #pragma unroll
        for (int j = 0; j < DPC; ++j) u[j] *= sc2;
    }

    if (e8 == 0) {   // lanes 0..7 cover the full 512 B fp32 output row
        float* dst = u_out + (size_t)t * DF + c * DPC;
        #pragma unroll
        for (int j = 0; j < DPC; j += 4)
            *reinterpret_cast<float4*>(dst + j) =
                make_float4(u[j], u[j+1], u[j+2], u[j+3]);
    }
}

extern "C" void kernel_launch(void* const* d_in, const int* in_sizes, int n_in,
                              void* d_out, int out_size, void* d_ws, size_t ws_size,
                              hipStream_t stream) {
    const void* x  = d_in[0];
    const int*  ei = (const int*)d_in[1];
    const int n_nodes = in_sizes[0] / DF;        // 50000
    const int n_edges = in_sizes[1] / 2;         // 800000
    const size_t NC = (size_t)n_nodes * DF;

    // ws: xcb bf16[NC/2 words, 12.8MB] | cnt[n] | flags[2] | elist[n*K]
    unsigned int* xcb = (unsigned int*)d_ws;
    int* cnt   = (int*)(xcb + NC / 2);
    int* flags = cnt + n_nodes;
    int* elist = flags + 2;

    size_t fixed = (size_t)(elist - (int*)d_ws) * 4;
    int K = 64;
    if (ws_size < fixed + (size_t)n_nodes * K * 4) {
        K = (int)((ws_size - fixed) / ((size_t)n_nodes * 4));
        if (K > 64) K = 64;
        if (K < 32) K = 32;      // statistically safe floor for lambda=16
    }

    float* u_out = (float*)d_out;

    const int tpb = 64 * WPB;                                    // 256
    const int nb_nodes  = (n_nodes + WPB - 1) / WPB;             // 12500
    const int nb_zero   = (n_nodes + 255) / 256 + 1;             // 197
    const int nb_bucket = (n_edges + 256 * EPT - 1) / (256 * EPT); // 782

    k_detect_zero<<<nb_zero, 256, 0, stream>>>(
        (const unsigned int*)x, (const unsigned int*)ei, flags, cnt, n_nodes);
    k_xc<<<nb_nodes, tpb, 0, stream>>>(x, xcb, flags, n_nodes);
    k_bucket<<<nb_bucket, 256, 0, stream>>>(ei, cnt, elist, flags,
                                            n_edges, n_nodes, K);
    k_route<<<nb_nodes, tpb, 0, stream>>>(cnt, elist, xcb, x, flags,
                                          u_out, n_nodes, K);
}

// Round 11
// 231.399 us; speedup vs baseline: 1.0243x; 1.0243x over previous
//
#include <hip/hip_runtime.h>
#include <hip/hip_bf16.h>

#define DF    128     // feature dim
#define DPC   16      // dims per capsule (8 caps)
#define WPB   4       // waves per 256-thread block
#define EPT   4       // edges per thread in bucket phase
#define SROWS 16      // neighbor rows staged in LDS per wave
#define RSTR  320     // LDS row stride bytes (2-way bank aliasing only)
#define CPAD  16      // cnt padding: 1 counter per 64B line

// ---------- helpers ----------
__device__ __forceinline__ float cap_sum(float v) {   // sum over lanes l..l|7
    v += __shfl_xor(v, 1);
    v += __shfl_xor(v, 2);
    v += __shfl_xor(v, 4);
    return v;
}
__device__ __forceinline__ float bits_lo(unsigned int w) {
    union { unsigned int u; float f; } c; c.u = w << 16; return c.f;
}
__device__ __forceinline__ float bits_hi(unsigned int w) {
    union { unsigned int u; float f; } c; c.u = w & 0xFFFF0000u; return c.f;
}
__device__ __forceinline__ unsigned int f2b_pack(float lo, float hi) {
    __hip_bfloat16 a = __float2bfloat16(lo), b = __float2bfloat16(hi);
    unsigned short ua = *reinterpret_cast<unsigned short*>(&a);
    unsigned short ub = *reinterpret_cast<unsigned short*>(&b);
    return ((unsigned int)ub << 16) | ua;
}
__device__ __forceinline__ float2 load_x2(const void* __restrict__ xraw, int fp32,
                                          int node, int lane) {
    size_t off = (size_t)node * DF + (size_t)lane * 2;
    if (fp32) {
        return *reinterpret_cast<const float2*>((const float*)xraw + off);
    } else {
        unsigned int w = ((const unsigned int*)xraw)[(size_t)node * 64 + lane];
        return make_float2(bits_lo(w), bits_hi(w));
    }
}
__device__ __forceinline__ int2 edge_st(const int* __restrict__ ei, int i64,
                                        int e, int n_edges) {
    size_t si = i64 ? (size_t)2 * e             : (size_t)e;
    size_t ti = i64 ? (size_t)2 * (n_edges + e) : (size_t)(n_edges + e);
    return make_int2(ei[si], ei[ti]);
}

// per-chunk routing math: dot, 8-cap softmax (no max-sub: |p|<=~1), weighted acc
__device__ __forceinline__ void proc_chunk(const uint4& w0, const uint4& w1,
                                           bool valid, const float* u, float* acc) {
    float z[DPC];
    z[0]  = bits_lo(w0.x); z[1]  = bits_hi(w0.x);
    z[2]  = bits_lo(w0.y); z[3]  = bits_hi(w0.y);
    z[4]  = bits_lo(w0.z); z[5]  = bits_hi(w0.z);
    z[6]  = bits_lo(w0.w); z[7]  = bits_hi(w0.w);
    z[8]  = bits_lo(w1.x); z[9]  = bits_hi(w1.x);
    z[10] = bits_lo(w1.y); z[11] = bits_hi(w1.y);
    z[12] = bits_lo(w1.z); z[13] = bits_hi(w1.z);
    z[14] = bits_lo(w1.w); z[15] = bits_hi(w1.w);
    float p = 0.0f;
    #pragma unroll
    for (int j = 0; j < DPC; ++j) p = fmaf(z[j], u[j], p);
    float ex = __expf(p);
    float sd = ex;
    sd += __shfl_xor(sd, 1);
    sd += __shfl_xor(sd, 2);
    sd += __shfl_xor(sd, 4);
    float w = valid ? ex * __builtin_amdgcn_rcpf(sd) : 0.0f;
    #pragma unroll
    for (int j = 0; j < DPC; ++j) acc[j] = fmaf(w, z[j], acc[j]);
}

// ---------- 1: detect dtypes (block 0) + zero padded cnt (blocks 1..) -------
__global__ void k_detect_zero(const unsigned int* __restrict__ xw,
                              const unsigned int* __restrict__ ew,
                              int* __restrict__ flags, int* __restrict__ cnt,
                              int n_cnt) {
    if (blockIdx.x == 0) {
        __shared__ int s_nan, s_zero;
        int tid = threadIdx.x;
        if (tid == 0) { s_nan = 0; s_zero = 0; }
        __syncthreads();
        int cnt_nan = 0;
        for (int i = tid; i < 4096; i += 256) {       // P(fp32 miss) ~ e^-16
            unsigned int lo = xw[i] & 0xFFFFu;
            if ((lo & 0x7F80u) == 0x7F80u) cnt_nan++; // impossible in bf16 data
        }
        int cnt_zero = 0;
        for (int i = tid; i < 1024; i += 256) {
            if (ew[2 * i + 1] == 0u) cnt_zero++;      // int64 high words zero
        }
        atomicAdd(&s_nan, cnt_nan);
        atomicAdd(&s_zero, cnt_zero);
        __syncthreads();
        if (tid == 0) {
            flags[0] = (s_nan > 0) ? 1 : 0;   // x is fp32
            flags[1] = (s_zero > 512) ? 1 : 0; // edge_index is int64
        }
    } else {
        int i = (blockIdx.x - 1) * 256 + threadIdx.x;
        if (i < n_cnt) cnt[i] = 0;
    }
}

// ---------- 2: fused xc(bf16, swizzled) + single-pass edge bucketing --------
// xc row (256 B): words [0,32) = caps' dims 0..7 (4 words per cap),
//                 words [32,64) = caps' dims 8..15.
// cnt is line-padded (stride CPAD): 1 counter / 64 B line -> 16x line parallelism.
__global__ void k_prep(const void* __restrict__ xraw, unsigned int* __restrict__ xcb,
                       const int* __restrict__ ei, int* __restrict__ cnt,
                       int* __restrict__ elist, const int* __restrict__ flags,
                       int n_nodes, int n_edges, int nb_bucket, int K) {
    const int fp32 = flags[0];
    int wid  = (blockIdx.x * blockDim.x + threadIdx.x) >> 6;
    int lane = threadIdx.x & 63;
    if (wid < n_nodes) {
        float2 v = load_x2(xraw, fp32, wid, lane);
        float ss = cap_sum(v.x * v.x + v.y * v.y);
        float scale = 1.0f / fmaxf(sqrtf(ss), 1e-12f);
        int c = lane >> 3, jp = lane & 7;
        int w = (jp < 4) ? (c * 4 + jp) : (32 + c * 4 + (jp - 4));
        xcb[(size_t)wid * 64 + w] = f2b_pack(v.x * scale, v.y * scale);
    }
    if (blockIdx.x < (unsigned)nb_bucket) {
        const int i64 = flags[1];
        int base = blockIdx.x * (256 * EPT) + threadIdx.x;
        int s[EPT], t[EPT], slot[EPT];
        bool ok[EPT];
        #pragma unroll
        for (int k = 0; k < EPT; ++k) {
            int e = base + k * 256;
            if (e < n_edges) {
                int2 st = edge_st(ei, i64, e, n_edges);
                s[k] = st.x; t[k] = st.y;
                ok[k] = (unsigned)st.x < (unsigned)n_nodes &&
                        (unsigned)st.y < (unsigned)n_nodes;
            } else ok[k] = false;
        }
        #pragma unroll
        for (int k = 0; k < EPT; ++k)
            if (ok[k]) slot[k] = atomicAdd(&cnt[t[k] * CPAD], 1);
        #pragma unroll
        for (int k = 0; k < EPT; ++k)
            if (ok[k] && slot[k] < K)
                elist[t[k] * K + slot[k]] = s[k] << 8;   // byte offset of row
    }
}

// ---------- 3: fused 3-iteration routing with LDS row staging ----------
// One wave per target. Lane = e8*8 + c. Iter 0 gathers from global (prefetch
// pipeline) and stages rows < SROWS in LDS; iters 1-2 read LDS (93% of
// traffic), global for overflow rows.
__global__ void k_route(const int* __restrict__ cnt, const int* __restrict__ elist,
                        const unsigned int* __restrict__ xcb,
                        const void* __restrict__ xraw, const int* __restrict__ flags,
                        float* __restrict__ u_out, int n_nodes, int K) {
    __shared__ char smem[WPB * SROWS * RSTR];            // 20480 B
    int t    = (blockIdx.x * blockDim.x + threadIdx.x) >> 6;
    int lane = threadIdx.x & 63;
    if (t >= n_nodes) return;
    const int e8 = lane >> 3;
    const int c  = lane & 7;
    const int fp32 = flags[0];
    char* my = smem + ((threadIdx.x >> 6) * SROWS) * RSTR;
    const int coff = c * 16;

    // target capsule c: 16 dims fp32-exact
    float xt[DPC];
    if (fp32) {
        const float* xp = (const float*)xraw + (size_t)t * DF + c * DPC;
        #pragma unroll
        for (int j = 0; j < DPC; j += 4) {
            float4 v = *reinterpret_cast<const float4*>(xp + j);
            xt[j] = v.x; xt[j+1] = v.y; xt[j+2] = v.z; xt[j+3] = v.w;
        }
    } else {
        const unsigned int* xp = (const unsigned int*)xraw + (size_t)t * 64 + c * 8;
        #pragma unroll
        for (int j = 0; j < DPC; j += 8) {
            uint4 w = *reinterpret_cast<const uint4*>(xp + j / 2);
            xt[j]   = bits_lo(w.x); xt[j+1] = bits_hi(w.x);
            xt[j+2] = bits_lo(w.y); xt[j+3] = bits_hi(w.y);
            xt[j+4] = bits_lo(w.z); xt[j+5] = bits_hi(w.z);
            xt[j+6] = bits_lo(w.w); xt[j+7] = bits_hi(w.w);
        }
    }
    float ss = 0.0f;
    #pragma unroll
    for (int j = 0; j < DPC; ++j) ss = fmaf(xt[j], xt[j], ss);
    float sc = 1.0f / fmaxf(sqrtf(ss), 1e-12f);
    float u[DPC];
    #pragma unroll
    for (int j = 0; j < DPC; ++j) { xt[j] *= sc; u[j] = xt[j]; }

    int deg = __builtin_amdgcn_readfirstlane(cnt[t * CPAD]);
    deg = min(deg, K);
    const int* __restrict__ erow = elist + (size_t)t * K;
    const char* __restrict__ xb  = (const char*)xcb;

    // ---- iteration 0: global gather (prefetched) + LDS staging ----
    float acc[DPC];
    #pragma unroll
    for (int j = 0; j < DPC; ++j) acc[j] = 0.0f;

    if (deg > 0) {
        uint4 cw0, cw1;
        {
            int off0 = erow[e8 < deg ? e8 : 0];
            cw0 = *reinterpret_cast<const uint4*>(xb + off0 + coff);
            cw1 = *reinterpret_cast<const uint4*>(xb + off0 + 128 + coff);
        }
        for (int base = 0; base < deg; base += 8) {
            uint4 nw0, nw1;
            bool havenext = (base + 8 < deg);
            if (havenext) {
                int ni = base + 8 + e8;
                int offn = erow[ni < deg ? ni : 0];
                nw0 = *reinterpret_cast<const uint4*>(xb + offn + coff);
                nw1 = *reinterpret_cast<const uint4*>(xb + offn + 128 + coff);
            }
            int row = base + e8;
            bool valid = row < deg;
            if (valid && row < SROWS) {        // stage for iters 1-2
                *reinterpret_cast<uint4*>(my + row * RSTR + coff)       = cw0;
                *reinterpret_cast<uint4*>(my + row * RSTR + 128 + coff) = cw1;
            }
            proc_chunk(cw0, cw1, valid, u, acc);
            if (havenext) { cw0 = nw0; cw1 = nw1; }
        }
    }
    #pragma unroll
    for (int j = 0; j < DPC; ++j) {
        acc[j] += __shfl_xor(acc[j], 8);
        acc[j] += __shfl_xor(acc[j], 16);
        acc[j] += __shfl_xor(acc[j], 32);
    }
    {
        float s2 = 0.0f;
        #pragma unroll
        for (int j = 0; j < DPC; ++j) {
            u[j] = acc[j] + xt[j];
            s2 = fmaf(u[j], u[j], s2);
        }
        float sc2 = 1.0f / fmaxf(sqrtf(s2), 1e-12f);
        #pragma unroll
        for (int j = 0; j < DPC; ++j) u[j] *= sc2;
    }

    // ---- iterations 1-2: LDS for rows < SROWS, global for the rest ----
    for (int it = 1; it < 3; ++it) {
        #pragma unroll
        for (int j = 0; j < DPC; ++j) acc[j] = 0.0f;
        for (int base = 0; base < deg; base += 8) {
            int row = base + e8;
            bool valid = row < deg;
            uint4 w0, w1;
            if (base < SROWS) {                // whole chunk staged
                int r = valid ? row : 0;
                w0 = *reinterpret_cast<const uint4*>(my + r * RSTR + coff);
                w1 = *reinterpret_cast<const uint4*>(my + r * RSTR + 128 + coff);
            } else {
                int off = erow[valid ? row : 0];
                w0 = *reinterpret_cast<const uint4*>(xb + off + coff);
                w1 = *reinterpret_cast<const uint4*>(xb + off + 128 + coff);
            }
            proc_chunk(w0, w1, valid, u, acc);
        }
        #pragma unroll
        for (int j = 0; j < DPC; ++j) {
            acc[j] += __shfl_xor(acc[j], 8);
            acc[j] += __shfl_xor(acc[j], 16);
            acc[j] += __shfl_xor(acc[j], 32);
        }
        float s2 = 0.0f;
        #pragma unroll
        for (int j = 0; j < DPC; ++j) {
            u[j] = acc[j] + xt[j];
            s2 = fmaf(u[j], u[j], s2);
        }
        float sc2 = 1.0f / fmaxf(sqrtf(s2), 1e-12f);
        #pragma unroll
        for (int j = 0; j < DPC; ++j) u[j] *= sc2;
    }

    if (e8 == 0) {   // lanes 0..7 cover the full 512 B fp32 output row
        float* dst = u_out + (size_t)t * DF + c * DPC;
        #pragma unroll
        for (int j = 0; j < DPC; j += 4)
            *reinterpret_cast<float4*>(dst + j) =
                make_float4(u[j], u[j+1], u[j+2], u[j+3]);
    }
}

extern "C" void kernel_launch(void* const* d_in, const int* in_sizes, int n_in,
                              void* d_out, int out_size, void* d_ws, size_t ws_size,
                              hipStream_t stream) {
    const void* x  = d_in[0];
    const int*  ei = (const int*)d_in[1];
    const int n_nodes = in_sizes[0] / DF;        // 50000
    const int n_edges = in_sizes[1] / 2;         // 800000
    const size_t NC = (size_t)n_nodes * DF;

    // ws: xcb bf16[NC/2 words, 12.8MB] | cnt[n*CPAD, 3.2MB] | flags[2] | elist[n*K]
    unsigned int* xcb = (unsigned int*)d_ws;
    int* cnt   = (int*)(xcb + NC / 2);
    int* flags = cnt + (size_t)n_nodes * CPAD;
    int* elist = flags + 2;

    size_t fixed = (size_t)(elist - (int*)d_ws) * 4;
    int K = 64;
    if (ws_size < fixed + (size_t)n_nodes * K * 4) {
        K = (int)((ws_size - fixed) / ((size_t)n_nodes * 4));
        if (K > 64) K = 64;
        if (K < 32) K = 32;      // statistically safe floor for lambda=16
    }

    float* u_out = (float*)d_out;

    const int tpb = 64 * WPB;                                      // 256
    const int n_cnt = n_nodes * CPAD;
    const int nb_nodes  = (n_nodes + WPB - 1) / WPB;               // 12500
    const int nb_zero   = (n_cnt + 255) / 256 + 1;                 // 3126
    const int nb_bucket = (n_edges + 256 * EPT - 1) / (256 * EPT); // 782

    k_detect_zero<<<nb_zero, 256, 0, stream>>>(
        (const unsigned int*)x, (const unsigned int*)ei, flags, cnt, n_cnt);
    k_prep<<<nb_nodes, tpb, 0, stream>>>(x, xcb, ei, cnt, elist, flags,
                                         n_nodes, n_edges, nb_bucket, K);
    k_route<<<nb_nodes, tpb, 0, stream>>>(cnt, elist, xcb, x, flags,
                                          u_out, n_nodes, K);
}